// Round 2
// baseline (281.050 us; speedup 1.0000x reference)
//
#include <hip/hip_runtime.h>
#include <math.h>

// ECT layer: ect[b,t,r] = sum_{n: batch[n]==b} sigmoid(8*(lin[r] - <x_n, v_t>))
// N=100000, D=3, T=64, R=64, B=128, lin = linspace(-1.1, 1.1, 64).
//
// VALU-bound: 4.1e8 sigmoids, ~4 MB real HBM traffic. Per-element cost cut to
// {fma, rcp, add} by the geometric-series trick: for fixed (n,t),
// exp(8*(nh-lin[r])) = e0 * kmul^r  -> ONE v_exp per 16 r's.
//
// Round-1 lesson: default occupancy heuristic capped VGPRs at 32 and spilled
// acc[16]/kp[16] to scratch (17% VALUBusy, 7x slowdown). Fix:
// __launch_bounds__(256,2) -> VGPR cap 128, no spill.
//
// Layout: block = NPB consecutive nodes (batch sorted). 256 threads own the
// full 64x64 (t,r) tile: t = tid>>2, r = (tid&3)*16 + j, j in [0,16) register
// accumulators. Segments of equal batch found via binary search in LDS
// (sorted), compute loop is branch-free; flush via atomicAdd per segment.

#define NPB 98       // ceil(100000/98) = 1021 blocks ~= 4/CU, balanced
#define THREADS 256

#if __has_builtin(__builtin_amdgcn_exp2f)
#define EXP2F(x) __builtin_amdgcn_exp2f(x)
#else
#define EXP2F(x) exp2f(x)
#endif
#if __has_builtin(__builtin_amdgcn_rcpf)
#define RCPF(x) __builtin_amdgcn_rcpf(x)
#else
#define RCPF(x) (1.0f / (x))
#endif

__global__ __launch_bounds__(THREADS, 2) void ECTLayer_kernel(
    const float* __restrict__ x,      // [N,3] row-major
    const float* __restrict__ v,      // [3,64] row-major
    const int*   __restrict__ batch,  // [N] sorted, 0..127
    float* __restrict__ out,          // [128,64,64] f32
    int n, float kmul)                // kmul = exp(-8*2.2/63)
{
    __shared__ float sx[NPB * 3];
    __shared__ int   sb[NPB];

    const int tid  = threadIdx.x;
    const int base = blockIdx.x * NPB;
    const int cnt  = min(NPB, n - base);

    for (int i = tid; i < cnt * 3; i += THREADS) sx[i] = x[base * 3 + i];
    for (int i = tid; i < cnt; i += THREADS)     sb[i] = batch[base + i];
    __syncthreads();

    const int t  = tid >> 2;       // direction index 0..63
    const int rg = tid & 3;        // r-group: r = rg*16 .. rg*16+15
    const float v0 = v[t], v1 = v[64 + t], v2 = v[128 + t];

    const float C2   = 11.541560327111707f;              // 8 * log2(e)
    const float lin0 = -1.1f + (float)(rg * 16) * (2.2f / 63.0f);
    const float u0   = -lin0 * C2;

    float kp[16], acc[16];
    kp[0] = 1.0f;
#pragma unroll
    for (int j = 1; j < 16; ++j) kp[j] = kp[j - 1] * kmul;
#pragma unroll
    for (int j = 0; j < 16; ++j) acc[j] = 0.0f;

    int i = 0;
    while (i < cnt) {
        const int b = sb[i];               // wave-uniform (LDS broadcast)
        // binary search last index of this segment (sb is sorted)
        int lo = i, hi = cnt;              // invariant: sb[lo] == b
        while (hi - lo > 1) {
            const int mid = (lo + hi) >> 1;
            if (sb[mid] == b) lo = mid; else hi = mid;
        }
        const int e = hi;                  // first index with a different b

        // branch-free compute over [i, e)
        for (; i < e; ++i) {
            const float x0 = sx[i * 3], x1 = sx[i * 3 + 1], x2 = sx[i * 3 + 2];
            const float nh = fmaf(x0, v0, fmaf(x1, v1, x2 * v2));
            const float e0 = EXP2F(fmaf(nh, C2, u0));   // exp(8*(nh - lin[rg*16]))
#pragma unroll
            for (int j = 0; j < 16; ++j)
                acc[j] += RCPF(fmaf(e0, kp[j], 1.0f));  // sigmoid(8*(lin[r]-nh))
        }

        // flush this batch's partial tile
        float* dst = out + ((size_t)b * 64 + t) * 64 + rg * 16;
#pragma unroll
        for (int j = 0; j < 16; ++j) { atomicAdd(dst + j, acc[j]); acc[j] = 0.0f; }
    }
}

extern "C" void kernel_launch(void* const* d_in, const int* in_sizes, int n_in,
                              void* d_out, int out_size, void* d_ws, size_t ws_size,
                              hipStream_t stream) {
    const float* x     = (const float*)d_in[0];
    const float* v     = (const float*)d_in[1];
    const int*   batch = (const int*)d_in[2];
    float*       out   = (float*)d_out;

    const int n = in_sizes[0] / 3;  // N nodes

    // Output is accumulated via atomics; harness poisons d_out and does not
    // re-zero between replays -> zero it every call (capture-safe memset).
    hipMemsetAsync(d_out, 0, (size_t)out_size * sizeof(float), stream);

    const float kmul = (float)exp(-8.0 * 2.2 / 63.0);  // per-r exp ratio
    const int nblocks = (n + NPB - 1) / NPB;
    hipLaunchKernelGGL(ECTLayer_kernel, dim3(nblocks), dim3(THREADS), 0, stream,
                       x, v, batch, out, n, kmul);
}

// Round 3
// 68.592 us; speedup vs baseline: 4.0974x; 4.0974x over previous
//
#include <hip/hip_runtime.h>
#include <math.h>

// ECT layer: ect[b,t,r] = sum_{n: batch[n]==b} sigmoid(8*(lin[r] - <x_n, v_t>))
// N=100000, D=3, T=64, R=64, B=128, lin = linspace(-1.1, 1.1, 64).
//
// Round-2 post-mortem: VALU issue time (VALUBusy*dur ~ 41us) matches the
// arithmetic floor; 85% of time is stall correlated with atomicAdd volume
// (WRITE_SIZE tracks atomic count exactly). Fix: NO atomics anywhere.
//   K0: segment boundaries of sorted batch -> seg[129] (ws)
//   K1: 128 segments x C chunks, each block = one (b,chunk) node range;
//       branch-free sigmoid accumulation in registers (geometric exp ladder:
//       ONE v_exp per 16 r's, then fma+rcp+add each); streaming store of the
//       64x64 partial tile to ws.
//   K2: reduce C partials per b -> out (fully overwritten, no memset).
// kp[16] ladder passed as kernel args -> SGPRs (frees VGPRs, independent fmas).

#define THREADS 256
#define TN 128          // nodes staged in LDS per tile
#define BSEG 128        // number of point clouds

#if __has_builtin(__builtin_amdgcn_exp2f)
#define EXP2F(x) __builtin_amdgcn_exp2f(x)
#else
#define EXP2F(x) exp2f(x)
#endif
#if __has_builtin(__builtin_amdgcn_rcpf)
#define RCPF(x) __builtin_amdgcn_rcpf(x)
#else
#define RCPF(x) (1.0f / (x))
#endif

struct Kp { float k[16]; };   // kp[j] = exp(-8*dlin)^j, passed via kernarg->SGPR

// --- K0: seg[b] = first node index with batch >= b; seg[BSEG] = n ---
__global__ void seg_bounds_kernel(const int* __restrict__ batch,
                                  int* __restrict__ seg, int n) {
    int i = blockIdx.x * blockDim.x + threadIdx.x;
    if (i >= n) return;
    const int a = batch[i];
    if (i == 0) {
        for (int bb = 0; bb <= a; ++bb) seg[bb] = 0;
    } else {
        const int p = batch[i - 1];
        for (int bb = p + 1; bb <= a; ++bb) seg[bb] = i;
    }
    if (i == n - 1) {
        for (int bb = a + 1; bb <= BSEG; ++bb) seg[bb] = n;
    }
}

// --- K1: per-(segment,chunk) partial 64x64 tile, no atomics ---
__global__ __launch_bounds__(THREADS, 4) void ect_partial_kernel(
    const float* __restrict__ x,      // [N,3]
    const float* __restrict__ v,      // [3,64]
    const int*   __restrict__ seg,    // [BSEG+1]
    float* __restrict__ partials,     // [BSEG*C, 4096]
    int C, Kp K)
{
    __shared__ float sx[TN * 3];

    const int tid = threadIdx.x;
    const int b   = blockIdx.x / C;
    const int c   = blockIdx.x - b * C;
    const int s0  = seg[b], s1 = seg[b + 1];
    const int len = s1 - s0;
    const int s   = s0 + (int)(((long long)len * c) / C);
    const int e   = s0 + (int)(((long long)len * (c + 1)) / C);

    const int t  = tid >> 2;       // direction 0..63
    const int rg = tid & 3;        // r-group: r = rg*16 + j
    const float v0 = v[t], v1 = v[64 + t], v2 = v[128 + t];

    const float C2   = 11.541560327111707f;              // 8*log2(e)
    const float lin0 = -1.1f + (float)(rg * 16) * (2.2f / 63.0f);
    const float u0   = -lin0 * C2;

    float acc[16];
#pragma unroll
    for (int j = 0; j < 16; ++j) acc[j] = 0.0f;

    for (int base = s; base < e; base += TN) {
        const int cnt = min(TN, e - base);
        __syncthreads();
        for (int i = tid; i < cnt * 3; i += THREADS)
            sx[i] = x[(size_t)base * 3 + i];
        __syncthreads();
        for (int i = 0; i < cnt; ++i) {
            const float x0 = sx[i * 3], x1 = sx[i * 3 + 1], x2 = sx[i * 3 + 2];
            const float nh = fmaf(x0, v0, fmaf(x1, v1, x2 * v2));
            const float e0 = EXP2F(fmaf(nh, C2, u0));   // exp(8*(nh - lin[rg*16]))
#pragma unroll
            for (int j = 0; j < 16; ++j)
                acc[j] += RCPF(fmaf(e0, K.k[j], 1.0f)); // sigmoid(8*(lin[r]-nh))
        }
    }

    // streaming store of this block's partial tile (always, even if empty:
    // ws is poisoned and K2 reads every slot)
    float4* dst = (float4*)(partials + (size_t)blockIdx.x * 4096 + tid * 16);
#pragma unroll
    for (int q = 0; q < 4; ++q)
        dst[q] = make_float4(acc[q * 4], acc[q * 4 + 1], acc[q * 4 + 2], acc[q * 4 + 3]);
}

// --- K2: out[b] = sum_c partials[b*C+c] ---
__global__ __launch_bounds__(THREADS) void ect_reduce_kernel(
    const float* __restrict__ partials, float* __restrict__ out, int C)
{
    const int b = blockIdx.x, tid = threadIdx.x;
    float4 a0 = {0,0,0,0}, a1 = {0,0,0,0}, a2 = {0,0,0,0}, a3 = {0,0,0,0};
    for (int c = 0; c < C; ++c) {
        const float4* p = (const float4*)(partials + ((size_t)(b * C + c)) * 4096 + tid * 16);
        float4 p0 = p[0], p1 = p[1], p2 = p[2], p3 = p[3];
        a0.x += p0.x; a0.y += p0.y; a0.z += p0.z; a0.w += p0.w;
        a1.x += p1.x; a1.y += p1.y; a1.z += p1.z; a1.w += p1.w;
        a2.x += p2.x; a2.y += p2.y; a2.z += p2.z; a2.w += p2.w;
        a3.x += p3.x; a3.y += p3.y; a3.z += p3.z; a3.w += p3.w;
    }
    float4* o = (float4*)(out + (size_t)b * 4096 + tid * 16);
    o[0] = a0; o[1] = a1; o[2] = a2; o[3] = a3;
}

extern "C" void kernel_launch(void* const* d_in, const int* in_sizes, int n_in,
                              void* d_out, int out_size, void* d_ws, size_t ws_size,
                              hipStream_t stream) {
    const float* x     = (const float*)d_in[0];
    const float* v     = (const float*)d_in[1];
    const int*   batch = (const int*)d_in[2];
    float*       out   = (float*)d_out;

    const int n = in_sizes[0] / 3;  // N nodes

    // ws layout: [0,4096) bytes = seg[129] ints; then partial tiles.
    int* seg = (int*)d_ws;
    float* partials = (float*)((char*)d_ws + 4096);

    // chunks per segment: want ~1024 blocks; clamp to what ws can hold.
    int C = 8;
    {
        size_t avail = (ws_size > 4096) ? (ws_size - 4096) : 0;
        size_t maxC = avail / ((size_t)BSEG * 4096 * sizeof(float));
        if (maxC < 1) maxC = 1;           // last resort (shouldn't happen)
        if ((size_t)C > maxC) C = (int)maxC;
    }

    Kp K;
    const double q = exp(-8.0 * 2.2 / 63.0);
    double p = 1.0;
    for (int j = 0; j < 16; ++j) { K.k[j] = (float)p; p *= q; }

    hipLaunchKernelGGL(seg_bounds_kernel, dim3((n + THREADS - 1) / THREADS),
                       dim3(THREADS), 0, stream, batch, seg, n);
    hipLaunchKernelGGL(ect_partial_kernel, dim3(BSEG * C), dim3(THREADS), 0, stream,
                       x, v, seg, partials, C, K);
    hipLaunchKernelGGL(ect_reduce_kernel, dim3(BSEG), dim3(THREADS), 0, stream,
                       partials, out, C);
}